// Round 2
// baseline (204.589 us; speedup 1.0000x reference)
//
#include <hip/hip_runtime.h>
#include <stdint.h>

typedef float f32x4 __attribute__((ext_vector_type(4)));
typedef __bf16 bf16x8 __attribute__((ext_vector_type(8)));

#define NROWS 65536   // 16 * 4096 x-rows
#define NCODES 4096
#define NDIM 64
#define NSPLIT 4      // stripes = waves per block
#define TILES 64      // 1024 codes per stripe / 16 per tile
#define CBMASK 0x3FFFF  // 4096*64 - 1 (bf16 element wrap for prefetch)
#define NCMASK 0xFFF    // 4096 - 1    (nc2h element wrap for prefetch)

// ws layout (bytes):
//   [0x000000, 0x080000): codes bf16      4096*64*2 = 512 KB
//   [0x080000, 0x084000): nc2h = -||c||^2/2  float[4096]
// All prefetch reads are wrapped with CBMASK/NCMASK -> never leave these regions.

__global__ __launch_bounds__(64) void prep_codes_k(const float* __restrict__ codes,
                                                   __bf16* __restrict__ cb,
                                                   float* __restrict__ nc2h) {
  int m = blockIdx.x * 64 + threadIdx.x;
  if (m >= NCODES) return;
  const float* src = codes + m * NDIM;
  float s = 0.f;
#pragma unroll
  for (int c = 0; c < 8; c++) {
    f32x4 v0 = *(const f32x4*)(src + c * 8);
    f32x4 v1 = *(const f32x4*)(src + c * 8 + 4);
    bf16x8 o;
#pragma unroll
    for (int j = 0; j < 4; j++) {
      o[j]     = (__bf16)v0[j];
      o[j + 4] = (__bf16)v1[j];
      s += v0[j] * v0[j] + v1[j] * v1[j];
    }
    *(bf16x8*)(cb + m * NDIM + c * 8) = o;
  }
  nc2h[m] = -0.5f * s;
}

// Block = 256 threads = 4 waves; wave w handles stripe w (1024 codes) for the
// SAME 32 rows. Cross-stripe argmax reduced in LDS; out[] written directly.
// A-frag (mfma_f32_16x16x32_bf16): lane holds A[m=lane&15][k=quad*8+j].
// C/D: col = lane&15, row = quad*4 + reg (m89/m91-verified).
// MFMA C-input preloaded with -||c||^2/2 so acc = dot - c2/2; argmax(acc) ==
// argmin d2, and d2 = x2 - 2*acc (exact *2).
__global__ __launch_bounds__(256, 6) void nn_fused(const float* __restrict__ x,
                                                   const __bf16* __restrict__ cb,
                                                   const float* __restrict__ nc2h,
                                                   int* __restrict__ out) {
  const int lane   = threadIdx.x & 63;
  const int stripe = threadIdx.x >> 6;  // 0..3
  const int col    = lane & 15;
  const int quad   = lane >> 4;
  const int rowbase = blockIdx.x * 32;

  __shared__ float rT[NSPLIT][32];
  __shared__ int   rM[NSPLIT][32];
  __shared__ float x2s[32];

  // ---- A fragments (fp32 -> bf16) + ||x||^2 ----
  bf16x8 a[2][2];
  float x2part[2];
#pragma unroll
  for (int rt = 0; rt < 2; rt++) {
    const float* xr = x + (rowbase + rt * 16 + col) * NDIM + quad * 8;
    float p = 0.f;
#pragma unroll
    for (int kc = 0; kc < 2; kc++) {
      f32x4 v0 = *(const f32x4*)(xr + kc * 32);
      f32x4 v1 = *(const f32x4*)(xr + kc * 32 + 4);
      bf16x8 af;
#pragma unroll
      for (int j = 0; j < 4; j++) {
        af[j]     = (__bf16)v0[j];
        af[j + 4] = (__bf16)v1[j];
        p += v0[j] * v0[j] + v1[j] * v1[j];
      }
      a[rt][kc] = af;
    }
    x2part[rt] = p;
  }
#pragma unroll
  for (int rt = 0; rt < 2; rt++) {
    float p = x2part[rt];
    p += __shfl_xor(p, 16);
    p += __shfl_xor(p, 32);
    x2part[rt] = p;
  }
  if (stripe == 0 && quad == 0) {
#pragma unroll
    for (int rt = 0; rt < 2; rt++) x2s[rt * 16 + col] = x2part[rt];
  }

  float bestT[2][4];
  int bestM[2][4];
#pragma unroll
  for (int rt = 0; rt < 2; rt++)
#pragma unroll
    for (int j = 0; j < 4; j++) {
      bestT[rt][j] = -3.0e38f;
      bestM[rt][j] = 0;
    }

  // 32-bit element offsets off uniform (SGPR) bases.
  uint32_t boff = (uint32_t)(stripe * 1024 + col) * NDIM + quad * 8;  // bf16 elems
  uint32_t noff = (uint32_t)(stripe * 1024 + col);                    // f32 elems

  // double-buffered B fragments, prefetch depth 2 tiles (wrapped, in-bounds)
  bf16x8 b0a = *(const bf16x8*)(cb + boff);
  bf16x8 b1a = *(const bf16x8*)(cb + boff + 32);
  float nva = nc2h[noff];
  bf16x8 b0b = *(const bf16x8*)(cb + boff + 1024);
  bf16x8 b1b = *(const bf16x8*)(cb + boff + 1056);
  float nvb = nc2h[noff + 16];

#pragma unroll 1
  for (int t = 0; t < TILES; t += 2) {
    // ---- tile t (set A) ----
    {
      f32x4 ci = {nva, nva, nva, nva};
      const int miA = (int)noff;
#pragma unroll
      for (int rt = 0; rt < 2; rt++) {
        f32x4 acc = __builtin_amdgcn_mfma_f32_16x16x32_bf16(a[rt][0], b0a, ci, 0, 0, 0);
        acc = __builtin_amdgcn_mfma_f32_16x16x32_bf16(a[rt][1], b1a, acc, 0, 0, 0);
#pragma unroll
        for (int j = 0; j < 4; j++) {
          if (acc[j] > bestT[rt][j]) {
            bestT[rt][j] = acc[j];
            bestM[rt][j] = miA;
          }
        }
      }
    }
    // prefetch tile t+2 into set A (offset wrapped -> always in-bounds)
    b0a = *(const bf16x8*)(cb + ((boff + 2048) & CBMASK));
    b1a = *(const bf16x8*)(cb + ((boff + 2080) & CBMASK));
    nva = nc2h[(noff + 32) & NCMASK];
    // ---- tile t+1 (set B) ----
    {
      f32x4 ci = {nvb, nvb, nvb, nvb};
      const int miB = (int)noff + 16;
#pragma unroll
      for (int rt = 0; rt < 2; rt++) {
        f32x4 acc = __builtin_amdgcn_mfma_f32_16x16x32_bf16(a[rt][0], b0b, ci, 0, 0, 0);
        acc = __builtin_amdgcn_mfma_f32_16x16x32_bf16(a[rt][1], b1b, acc, 0, 0, 0);
#pragma unroll
        for (int j = 0; j < 4; j++) {
          if (acc[j] > bestT[rt][j]) {
            bestT[rt][j] = acc[j];
            bestM[rt][j] = miB;
          }
        }
      }
    }
    // prefetch tile t+3 into set B (wrapped)
    b0b = *(const bf16x8*)(cb + ((boff + 3072) & CBMASK));
    b1b = *(const bf16x8*)(cb + ((boff + 3104) & CBMASK));
    nvb = nc2h[(noff + 48) & NCMASK];
    boff += 2048;
    noff += 32;
  }

  // ---- butterfly argmax across the 16 lanes sharing each row ----
#pragma unroll
  for (int rt = 0; rt < 2; rt++) {
#pragma unroll
    for (int j = 0; j < 4; j++) {
      float bt = bestT[rt][j];
      int bm = bestM[rt][j];
#pragma unroll
      for (int off = 1; off < 16; off <<= 1) {
        float ot = __shfl_xor(bt, off);
        int om = __shfl_xor(bm, off);
        if (ot > bt || (ot == bt && om < bm)) {
          bt = ot;
          bm = om;
        }
      }
      if (col == 0) {
        rT[stripe][rt * 16 + quad * 4 + j] = bt;
        rM[stripe][rt * 16 + quad * 4 + j] = bm;
      }
    }
  }
  __syncthreads();

  // ---- cross-stripe reduce + threshold + store (threads 0..31) ----
  if (threadIdx.x < 32) {
    const int r = threadIdx.x;
    float bt = rT[0][r];
    int bm = rM[0][r];
#pragma unroll
    for (int s = 1; s < NSPLIT; s++) {
      float tv = rT[s][r];
      int m = rM[s][r];
      if (tv > bt || (tv == bt && m < bm)) {
        bt = tv;
        bm = m;
      }
    }
    const float d2 = fmaf(-2.0f, bt, x2s[r]);  // min squared distance
    out[rowbase + r] = (d2 <= 0.1f) ? bm : -1;
  }
}

extern "C" void kernel_launch(void* const* d_in, const int* in_sizes, int n_in,
                              void* d_out, int out_size, void* d_ws, size_t ws_size,
                              hipStream_t stream) {
  const float* x = (const float*)d_in[0];      // [65536][64] fp32
  const float* codes = (const float*)d_in[1];  // [4096][64] fp32
  int* out = (int*)d_out;                      // [65536] int32

  char* ws = (char*)d_ws;
  __bf16* cb = (__bf16*)ws;              // 512 KB
  float* nc2h = (float*)(ws + 0x080000); // 16 KB

  prep_codes_k<<<NCODES / 64, 64, 0, stream>>>(codes, cb, nc2h);
  nn_fused<<<NROWS / 32, 256, 0, stream>>>(x, cb, nc2h, out);
}

// Round 3
// 139.905 us; speedup vs baseline: 1.4623x; 1.4623x over previous
//
#include <hip/hip_runtime.h>
#include <stdint.h>

typedef float f32x4 __attribute__((ext_vector_type(4)));
typedef __bf16 bf16x8 __attribute__((ext_vector_type(8)));

#define NROWS 65536   // 16 * 4096 x-rows
#define NCODES 4096
#define NDIM 64
#define NSPLIT 4      // stripes = waves per block
#define TILES 64      // 1024 codes per stripe / 16 per tile
#define DEPTH 4       // register-ring prefetch depth (tiles)
#define CBMASK 0x3FFFF  // 4096*64 - 1 (bf16 element wrap for tail prefetch)

// ws layout (bytes):
//   [0x000000, 0x080000): codes bf16      4096*64*2 = 512 KB
//   [0x080000, 0x084000): nc2h = -||c||^2/2  float[4096]
// Tail prefetches wrap via CBMASK -> never leave these regions.

__global__ __launch_bounds__(64) void prep_codes_k(const float* __restrict__ codes,
                                                   __bf16* __restrict__ cb,
                                                   float* __restrict__ nc2h) {
  int m = blockIdx.x * 64 + threadIdx.x;
  if (m >= NCODES) return;
  const float* src = codes + m * NDIM;
  float s = 0.f;
#pragma unroll
  for (int c = 0; c < 8; c++) {
    f32x4 v0 = *(const f32x4*)(src + c * 8);
    f32x4 v1 = *(const f32x4*)(src + c * 8 + 4);
    bf16x8 o;
#pragma unroll
    for (int j = 0; j < 4; j++) {
      o[j]     = (__bf16)v0[j];
      o[j + 4] = (__bf16)v1[j];
      s += v0[j] * v0[j] + v1[j] * v1[j];
    }
    *(bf16x8*)(cb + m * NDIM + c * 8) = o;
  }
  nc2h[m] = -0.5f * s;
}

// Block = 256 threads = 4 waves; wave w = stripe w (1024 codes) for the SAME
// 64 rows (4 row-tiles of 16). Grid = 1024 blocks -> 4 blocks/CU, 4 waves/SIMD
// (grid-capped), so up to 128 VGPR/wave is free -> spend on a depth-4 ring.
// A-frag (mfma_f32_16x16x32_bf16): lane holds A[m=lane&15][k=quad*8+j].
// C/D: col(n) = lane&15, row(m) = quad*4 + reg (m89/m91-verified).
// MFMA C-init = -||c||^2/2 so acc = dot - c2/2; argmax(acc) == argmin d2;
// d2 = x2 - 2*acc (exact *2).
__global__ __launch_bounds__(256, 4) void nn_fused(const float* __restrict__ x,
                                                   const __bf16* __restrict__ cb,
                                                   const float* __restrict__ nc2h,
                                                   int* __restrict__ out) {
  const int lane   = threadIdx.x & 63;
  const int stripe = threadIdx.x >> 6;  // 0..3
  const int col    = lane & 15;
  const int quad   = lane >> 4;
  const int rowbase = blockIdx.x * 64;

  __shared__ float rT[NSPLIT][64];
  __shared__ int   rM[NSPLIT][64];
  __shared__ float x2s[64];

  // ---- A fragments (fp32 -> bf16) + ||x||^2 ----
  bf16x8 a[4][2];
  float x2part[4];
#pragma unroll
  for (int rt = 0; rt < 4; rt++) {
    const float* xr = x + (rowbase + rt * 16 + col) * NDIM + quad * 8;
    float p = 0.f;
#pragma unroll
    for (int kc = 0; kc < 2; kc++) {
      f32x4 v0 = *(const f32x4*)(xr + kc * 32);
      f32x4 v1 = *(const f32x4*)(xr + kc * 32 + 4);
      bf16x8 af;
#pragma unroll
      for (int j = 0; j < 4; j++) {
        af[j]     = (__bf16)v0[j];
        af[j + 4] = (__bf16)v1[j];
        p += v0[j] * v0[j] + v1[j] * v1[j];
      }
      a[rt][kc] = af;
    }
    x2part[rt] = p;
  }
#pragma unroll
  for (int rt = 0; rt < 4; rt++) {
    float p = x2part[rt];
    p += __shfl_xor(p, 16);
    p += __shfl_xor(p, 32);
    x2part[rt] = p;
  }
  if (stripe == 0 && quad == 0) {
#pragma unroll
    for (int rt = 0; rt < 4; rt++) x2s[rt * 16 + col] = x2part[rt];
  }

  float bestT[4][4];
  int bestM[4][4];
#pragma unroll
  for (int rt = 0; rt < 4; rt++)
#pragma unroll
    for (int j = 0; j < 4; j++) {
      bestT[rt][j] = -3.0e38f;
      bestM[rt][j] = 0;
    }

  // 32-bit element offsets off uniform (SGPR) bases.
  uint32_t poff = (uint32_t)(stripe * 1024 + col) * NDIM + quad * 8;  // bf16 elems
  uint32_t cidx = (uint32_t)(stripe * 1024 + col);  // code index of compute tile

  // ---- depth-4 register ring: prologue fills tiles 0..3 ----
  bf16x8 b0[DEPTH], b1[DEPTH];
  float nv[DEPTH];
#pragma unroll
  for (int k = 0; k < DEPTH; k++) {
    b0[k] = *(const bf16x8*)(cb + poff);
    b1[k] = *(const bf16x8*)(cb + poff + 32);
    nv[k] = nc2h[poff >> 6];
    poff += 1024;  // 16 code rows * 64 dims
  }

#pragma unroll 1
  for (int it = 0; it < TILES / DEPTH; ++it) {
#pragma unroll
    for (int k = 0; k < DEPTH; k++) {
      // ---- consume buffer k (tile t = it*DEPTH + k) ----
      f32x4 ci = {nv[k], nv[k], nv[k], nv[k]};
      const int mi = (int)cidx;
#pragma unroll
      for (int rt = 0; rt < 4; rt++) {
        f32x4 acc = __builtin_amdgcn_mfma_f32_16x16x32_bf16(a[rt][0], b0[k], ci, 0, 0, 0);
        acc = __builtin_amdgcn_mfma_f32_16x16x32_bf16(a[rt][1], b1[k], acc, 0, 0, 0);
#pragma unroll
        for (int j = 0; j < 4; j++) {
          if (acc[j] > bestT[rt][j]) {
            bestT[rt][j] = acc[j];
            bestM[rt][j] = mi;
          }
        }
      }
      // ---- reload buffer k with tile t+DEPTH (no temps, no movs; wrapped) ----
      const uint32_t pm = poff & CBMASK;
      b0[k] = *(const bf16x8*)(cb + pm);
      b1[k] = *(const bf16x8*)(cb + pm + 32);
      nv[k] = nc2h[pm >> 6];
      poff += 1024;
      cidx += 16;
    }
  }

  // ---- butterfly argmax across the 16 lanes sharing each row ----
#pragma unroll
  for (int rt = 0; rt < 4; rt++) {
#pragma unroll
    for (int j = 0; j < 4; j++) {
      float bt = bestT[rt][j];
      int bm = bestM[rt][j];
#pragma unroll
      for (int off = 1; off < 16; off <<= 1) {
        float ot = __shfl_xor(bt, off);
        int om = __shfl_xor(bm, off);
        if (ot > bt || (ot == bt && om < bm)) {
          bt = ot;
          bm = om;
        }
      }
      if (col == 0) {
        rT[stripe][rt * 16 + quad * 4 + j] = bt;
        rM[stripe][rt * 16 + quad * 4 + j] = bm;
      }
    }
  }
  __syncthreads();

  // ---- cross-stripe reduce + threshold + store (threads 0..63) ----
  if (threadIdx.x < 64) {
    const int r = threadIdx.x;
    float bt = rT[0][r];
    int bm = rM[0][r];
#pragma unroll
    for (int s = 1; s < NSPLIT; s++) {
      float tv = rT[s][r];
      int m = rM[s][r];
      if (tv > bt || (tv == bt && m < bm)) {
        bt = tv;
        bm = m;
      }
    }
    const float d2 = fmaf(-2.0f, bt, x2s[r]);  // min squared distance
    out[rowbase + r] = (d2 <= 0.1f) ? bm : -1;
  }
}

extern "C" void kernel_launch(void* const* d_in, const int* in_sizes, int n_in,
                              void* d_out, int out_size, void* d_ws, size_t ws_size,
                              hipStream_t stream) {
  const float* x = (const float*)d_in[0];      // [65536][64] fp32
  const float* codes = (const float*)d_in[1];  // [4096][64] fp32
  int* out = (int*)d_out;                      // [65536] int32

  char* ws = (char*)d_ws;
  __bf16* cb = (__bf16*)ws;              // 512 KB
  float* nc2h = (float*)(ws + 0x080000); // 16 KB

  prep_codes_k<<<NCODES / 64, 64, 0, stream>>>(codes, cb, nc2h);
  nn_fused<<<NROWS / 64, 256, 0, stream>>>(x, cb, nc2h, out);
}

// Round 4
// 135.510 us; speedup vs baseline: 1.5098x; 1.0324x over previous
//
#include <hip/hip_runtime.h>
#include <stdint.h>

typedef float f32x4 __attribute__((ext_vector_type(4)));
typedef __bf16 bf16x8 __attribute__((ext_vector_type(8)));
typedef __bf16 bf16x4 __attribute__((ext_vector_type(4)));

#define NROWS 65536   // 16 * 4096 x-rows
#define NCODES 4096
#define NDIM 64
#define NSPLIT 4      // stripes = waves per block
#define STEPS 32      // 1024 codes per stripe / 32 codes per step
#define CBMASK 0x3FFFF  // 4096*64 - 1 (bf16 element wrap for tail prefetch)
#define NCMASK 0xFFF

// ws layout (bytes):
//   [0x000000, 0x080000): codes bf16      4096*64*2 = 512 KB
//   [0x080000, 0x084000): nc2h = -||c||^2/2  float[4096]
// Tail prefetches wrap via CBMASK (worst case 64B spill into nc2h region,
// values never consumed) -> all reads stay inside ws.

// Coalesced prep: 65536 threads, one f32x4 per thread; 16 lanes per code row;
// shfl_xor 16-lane reduce for -||c||^2/2. (Old version: 64 waves, 256B-strided
// uncoalesced reads -> ~40us. This: ~3us.)
__global__ __launch_bounds__(256) void prep_codes_k(const float* __restrict__ codes,
                                                    float* __restrict__ nc2h,
                                                    __bf16* __restrict__ cb) {
  const int t = blockIdx.x * 256 + threadIdx.x;  // 0..65535
  f32x4 v = *(const f32x4*)(codes + t * 4);
  bf16x4 o;
  float s = 0.f;
#pragma unroll
  for (int j = 0; j < 4; j++) {
    o[j] = (__bf16)v[j];
    s += v[j] * v[j];
  }
  *(bf16x4*)(cb + t * 4) = o;
  s += __shfl_xor(s, 1);
  s += __shfl_xor(s, 2);
  s += __shfl_xor(s, 4);
  s += __shfl_xor(s, 8);
  if ((threadIdx.x & 15) == 0) nc2h[t >> 4] = -0.5f * s;
}

// Block = 256 threads = 4 waves; wave w = stripe w (1024 codes) for the SAME
// 64 rows. 32 steps of 32 codes (2 code-tiles): 16 MFMA per step -> half the
// step-slots of r3 (per-step latency was shown to be the wall-time currency).
// A-frag (mfma_f32_16x16x32_bf16): lane holds A[m=lane&15][k=quad*8+j].
// C/D: col(n) = lane&15, row(m) = quad*4 + reg (m89/m91-verified).
// MFMA C-init = -||c||^2/2 so acc = dot - c2/2; argmax(acc) == argmin d2;
// d2 = x2 - 2*acc (exact *2). Strict '>' + ascending code order keeps the
// lowest-index argmax (matches jnp.argmin first-min semantics).
__global__ __launch_bounds__(256, 4) void nn_fused(const float* __restrict__ x,
                                                   const __bf16* __restrict__ cb,
                                                   const float* __restrict__ nc2h,
                                                   int* __restrict__ out) {
  const int lane   = threadIdx.x & 63;
  const int stripe = threadIdx.x >> 6;  // 0..3
  const int col    = lane & 15;
  const int quad   = lane >> 4;
  const int rowbase = blockIdx.x * 64;

  __shared__ float rT[NSPLIT][64];
  __shared__ int   rM[NSPLIT][64];
  __shared__ float x2s[64];

  // ---- A fragments (fp32 -> bf16) + ||x||^2 ----
  bf16x8 a[4][2];
  float x2part[4];
#pragma unroll
  for (int rt = 0; rt < 4; rt++) {
    const float* xr = x + (rowbase + rt * 16 + col) * NDIM + quad * 8;
    float p = 0.f;
#pragma unroll
    for (int kc = 0; kc < 2; kc++) {
      f32x4 v0 = *(const f32x4*)(xr + kc * 32);
      f32x4 v1 = *(const f32x4*)(xr + kc * 32 + 4);
      bf16x8 af;
#pragma unroll
      for (int j = 0; j < 4; j++) {
        af[j]     = (__bf16)v0[j];
        af[j + 4] = (__bf16)v1[j];
        p += v0[j] * v0[j] + v1[j] * v1[j];
      }
      a[rt][kc] = af;
    }
    x2part[rt] = p;
  }
#pragma unroll
  for (int rt = 0; rt < 4; rt++) {
    float p = x2part[rt];
    p += __shfl_xor(p, 16);
    p += __shfl_xor(p, 32);
    x2part[rt] = p;
  }
  if (stripe == 0 && quad == 0) {
#pragma unroll
    for (int rt = 0; rt < 4; rt++) x2s[rt * 16 + col] = x2part[rt];
  }

  float bestT[4][4];
  int bestM[4][4];
#pragma unroll
  for (int rt = 0; rt < 4; rt++)
#pragma unroll
    for (int j = 0; j < 4; j++) {
      bestT[rt][j] = -3.0e38f;
      bestM[rt][j] = 0;
    }

  // 32-bit element offsets off uniform (SGPR) bases.
  uint32_t poff = (uint32_t)(stripe * 1024 + col) * NDIM + quad * 8;  // bf16 elems
  uint32_t cidx = (uint32_t)(stripe * 1024 + col);  // code index of compute step

  // ---- ring of 2 steps x 2 code-tiles; prologue fills steps 0,1 ----
  bf16x8 b[2][2][2];
  float nv[2][2];
#pragma unroll
  for (int k = 0; k < 2; k++) {
#pragma unroll
    for (int ct = 0; ct < 2; ct++) {
      const uint32_t o = poff + k * 2048 + ct * 1024;
      b[k][ct][0] = *(const bf16x8*)(cb + o);
      b[k][ct][1] = *(const bf16x8*)(cb + o + 32);
      nv[k][ct] = nc2h[o >> 6];  // = code + k*32 + ct*16
    }
  }
  poff += 4096;  // points at step 2

#pragma unroll 1
  for (int it = 0; it < STEPS / 2; ++it) {
#pragma unroll
    for (int k = 0; k < 2; k++) {
      // ---- consume buffer k (step s = it*2 + k): 32 codes ----
      f32x4 ci0 = {nv[k][0], nv[k][0], nv[k][0], nv[k][0]};
      f32x4 ci1 = {nv[k][1], nv[k][1], nv[k][1], nv[k][1]};
      const int mi0 = (int)cidx;
      const int mi1 = (int)cidx + 16;
#pragma unroll
      for (int rt = 0; rt < 4; rt++) {
        f32x4 acc0 = __builtin_amdgcn_mfma_f32_16x16x32_bf16(a[rt][0], b[k][0][0], ci0, 0, 0, 0);
        acc0 = __builtin_amdgcn_mfma_f32_16x16x32_bf16(a[rt][1], b[k][0][1], acc0, 0, 0, 0);
        f32x4 acc1 = __builtin_amdgcn_mfma_f32_16x16x32_bf16(a[rt][0], b[k][1][0], ci1, 0, 0, 0);
        acc1 = __builtin_amdgcn_mfma_f32_16x16x32_bf16(a[rt][1], b[k][1][1], acc1, 0, 0, 0);
#pragma unroll
        for (int j = 0; j < 4; j++) {
          if (acc0[j] > bestT[rt][j]) {
            bestT[rt][j] = acc0[j];
            bestM[rt][j] = mi0;
          }
          if (acc1[j] > bestT[rt][j]) {
            bestT[rt][j] = acc1[j];
            bestM[rt][j] = mi1;
          }
        }
      }
      // ---- reload buffer k with step s+2 (wrapped; tail values never consumed) ----
#pragma unroll
      for (int ct = 0; ct < 2; ct++) {
        const uint32_t o = (poff + ct * 1024) & CBMASK;
        b[k][ct][0] = *(const bf16x8*)(cb + o);
        b[k][ct][1] = *(const bf16x8*)(cb + o + 32);
        nv[k][ct] = nc2h[(o >> 6) & NCMASK];
      }
      poff += 2048;
      cidx += 32;
    }
  }

  // ---- butterfly argmax across the 16 lanes sharing each row ----
#pragma unroll
  for (int rt = 0; rt < 4; rt++) {
#pragma unroll
    for (int j = 0; j < 4; j++) {
      float bt = bestT[rt][j];
      int bm = bestM[rt][j];
#pragma unroll
      for (int off = 1; off < 16; off <<= 1) {
        float ot = __shfl_xor(bt, off);
        int om = __shfl_xor(bm, off);
        if (ot > bt || (ot == bt && om < bm)) {
          bt = ot;
          bm = om;
        }
      }
      if (col == 0) {
        rT[stripe][rt * 16 + quad * 4 + j] = bt;
        rM[stripe][rt * 16 + quad * 4 + j] = bm;
      }
    }
  }
  __syncthreads();

  // ---- cross-stripe reduce + threshold + store (threads 0..63) ----
  if (threadIdx.x < 64) {
    const int r = threadIdx.x;
    float bt = rT[0][r];
    int bm = rM[0][r];
#pragma unroll
    for (int s = 1; s < NSPLIT; s++) {
      float tv = rT[s][r];
      int m = rM[s][r];
      if (tv > bt || (tv == bt && m < bm)) {
        bt = tv;
        bm = m;
      }
    }
    const float d2 = fmaf(-2.0f, bt, x2s[r]);  // min squared distance
    out[rowbase + r] = (d2 <= 0.1f) ? bm : -1;
  }
}

extern "C" void kernel_launch(void* const* d_in, const int* in_sizes, int n_in,
                              void* d_out, int out_size, void* d_ws, size_t ws_size,
                              hipStream_t stream) {
  const float* x = (const float*)d_in[0];      // [65536][64] fp32
  const float* codes = (const float*)d_in[1];  // [4096][64] fp32
  int* out = (int*)d_out;                      // [65536] int32

  char* ws = (char*)d_ws;
  __bf16* cb = (__bf16*)ws;              // 512 KB
  float* nc2h = (float*)(ws + 0x080000); // 16 KB

  prep_codes_k<<<NROWS / 256 / 16 * 16, 256, 0, stream>>>(codes, nc2h, cb);  // 256 blocks
  nn_fused<<<NROWS / 64, 256, 0, stream>>>(x, cb, nc2h, out);
}

// Round 6
// 117.148 us; speedup vs baseline: 1.7464x; 1.1567x over previous
//
#include <hip/hip_runtime.h>
#include <stdint.h>

typedef float f32x4 __attribute__((ext_vector_type(4)));
typedef __bf16 bf16x8 __attribute__((ext_vector_type(8)));
typedef __bf16 bf16x4 __attribute__((ext_vector_type(4)));

#define NROWS 65536     // 16 * 4096 x-rows
#define NCODES 4096
#define NDIM 64
#define NSPLIT 4        // code stripes (cross-BLOCK)
#define STEPS 32        // 1024 codes per stripe / 32 codes per step
#define CBBYTEMASK 0x7FFFF  // 512KB cb region byte wrap (tail prefetch safety)
#define NCMASK 0xFFF

// ws layout (bytes):
//   [0x000000, 0x080000): codes bf16        4096*64*2 = 512 KB
//   [0x080000, 0x084000): nc2h = -||c||^2/2 float[4096]
//   [0x100000, 0x200000): tarr float[NROWS*NSPLIT]
//   [0x200000, 0x300000): marr int  [NROWS*NSPLIT]
//   [0x300000, 0x340000): x2   float[NROWS]

__device__ __forceinline__ void gld_lds16(const void* g, void* l) {
  __builtin_amdgcn_global_load_lds(
      (const __attribute__((address_space(1))) unsigned int*)g,
      (__attribute__((address_space(3))) unsigned int*)l, 16, 0, 0);
}

// Coalesced prep: 65536 threads, one f32x4 each; 16 lanes per code row.
__global__ __launch_bounds__(256) void prep_codes_k(const float* __restrict__ codes,
                                                    float* __restrict__ nc2h,
                                                    __bf16* __restrict__ cb) {
  const int t = blockIdx.x * 256 + threadIdx.x;  // 0..65535
  f32x4 v = *(const f32x4*)(codes + t * 4);
  bf16x4 o;
  float s = 0.f;
#pragma unroll
  for (int j = 0; j < 4; j++) {
    o[j] = (__bf16)v[j];
    s += v[j] * v[j];
  }
  *(bf16x4*)(cb + t * 4) = o;
  s += __shfl_xor(s, 1);
  s += __shfl_xor(s, 2);
  s += __shfl_xor(s, 4);
  s += __shfl_xor(s, 8);
  if ((threadIdx.x & 15) == 0) nc2h[t >> 4] = -0.5f * s;
}

// Block = 256 thr = 4 waves sharing ONE 1024-code stripe through LDS; wave w
// owns 64 rows. Per 32-code step: stage the 4KB B-tile ONCE per block
// (global_load_lds 16B x 256 thr, XOR-pre-swizzled source), all waves ds_read.
// Swizzle involution (rule #21): LDS[addr]=G[addr^((addr>>7&7)<<4)] on store,
// reader XORs the same -> identity; and ds_read_b128 is bank-spread.
// A-frag (mfma_f32_16x16x32_bf16): lane holds A[m=lane&15][k=quad*8+j].
// C/D: col(n)=lane&15, row(m)=quad*4+reg (m89/m91-verified).
// MFMA C-init = -||c||^2/2 so acc = dot - c2/2; argmax(acc)==argmin d2;
// d2 = x2 - 2*acc (exact *2). Strict '>' + ascending order => lowest index.
__global__ __launch_bounds__(256, 4) void nn_main(const float* __restrict__ x,
                                                  const __bf16* __restrict__ cbv,
                                                  const float* __restrict__ nc2h,
                                                  float* __restrict__ tarr,
                                                  int* __restrict__ marr,
                                                  float* __restrict__ x2arr) {
  const int tid  = threadIdx.x;
  const int lane = tid & 63;
  const int w    = tid >> 6;   // wave id = row chunk
  const int col  = lane & 15;
  const int quad = lane >> 4;
  const int stripe = blockIdx.x & 3;
  const int rowgrp = blockIdx.x >> 2;      // 0..255
  const int rowbase = rowgrp * 256 + w * 64;
  const char* cbb = (const char*)cbv;

  __shared__ __align__(16) char stage[2][4096];

  // ---- A fragments (fp32 -> bf16) + ||x||^2 ----
  bf16x8 a[4][2];
  float x2part[4];
#pragma unroll
  for (int rt = 0; rt < 4; rt++) {
    const float* xr = x + (rowbase + rt * 16 + col) * NDIM + quad * 8;
    float p = 0.f;
#pragma unroll
    for (int kc = 0; kc < 2; kc++) {
      f32x4 v0 = *(const f32x4*)(xr + kc * 32);
      f32x4 v1 = *(const f32x4*)(xr + kc * 32 + 4);
      bf16x8 af;
#pragma unroll
      for (int j = 0; j < 4; j++) {
        af[j]     = (__bf16)v0[j];
        af[j + 4] = (__bf16)v1[j];
        p += v0[j] * v0[j] + v1[j] * v1[j];
      }
      a[rt][kc] = af;
    }
    x2part[rt] = p;
  }
#pragma unroll
  for (int rt = 0; rt < 4; rt++) {
    float p = x2part[rt];
    p += __shfl_xor(p, 16);
    p += __shfl_xor(p, 32);
    x2part[rt] = p;
  }
  if (stripe == 0 && quad == 0) {
#pragma unroll
    for (int rt = 0; rt < 4; rt++) x2arr[rowbase + rt * 16 + col] = x2part[rt];
  }

  float bestT[4][4];
  int bestM[4][4];
#pragma unroll
  for (int rt = 0; rt < 4; rt++)
#pragma unroll
    for (int j = 0; j < 4; j++) {
      bestT[rt][j] = -3.0e38f;
      bestM[rt][j] = 0;
    }

  // ---- staging source (pre-swizzled so linear LDS dest + XOR read is identity) ----
  const uint32_t schunk = ((uint32_t)(tid * 16)) ^ ((((uint32_t)tid >> 3) & 7u) << 4);
  uint32_t sbyte = (uint32_t)stripe * 131072u + schunk;  // step-0 tile chunk
  char* ldst0 = &stage[0][w * 1024];  // wave-uniform dest; HW adds lane*16
  char* ldst1 = &stage[1][w * 1024];

  // ---- reader LDS byte offsets (swizzled) ----
  const uint32_t swz = ((uint32_t)(col & 7)) << 4;
  const uint32_t o00 = ((uint32_t)(col * 128 + quad * 16)) ^ swz;
  const uint32_t o01 = ((uint32_t)(col * 128 + 64 + quad * 16)) ^ swz;
  const uint32_t o10 = ((uint32_t)(2048 + col * 128 + quad * 16)) ^ swz;
  const uint32_t o11 = ((uint32_t)(2048 + col * 128 + 64 + quad * 16)) ^ swz;

  const int nb = stripe * 1024 + col;
  float nv0 = nc2h[nb];
  float nv1 = nc2h[nb + 16];

  gld_lds16(cbb + (sbyte & CBBYTEMASK), ldst0);  // stage step 0 -> buf0
  sbyte += 4096;
  __syncthreads();  // vmcnt drained -> buf0 ready

  int mi = stripe * 1024 + col;  // per-lane code id of compute step

#pragma unroll 1
  for (int s = 0; s < STEPS; s += 2) {
    // ===== step s: read buf0, stage s+1 -> buf1 =====
    gld_lds16(cbb + (sbyte & CBBYTEMASK), ldst1);
    sbyte += 4096;
    uint32_t nxt = (uint32_t)(nb + (s + 1) * 32);
    float nv0n = nc2h[nxt & NCMASK];
    float nv1n = nc2h[(nxt + 16) & NCMASK];
    {
      const char* sb = stage[0];
      bf16x8 b00 = *(const bf16x8*)(sb + o00);
      bf16x8 b01 = *(const bf16x8*)(sb + o01);
      bf16x8 b10 = *(const bf16x8*)(sb + o10);
      bf16x8 b11 = *(const bf16x8*)(sb + o11);
      f32x4 ci0 = {nv0, nv0, nv0, nv0};
      f32x4 ci1 = {nv1, nv1, nv1, nv1};
#pragma unroll
      for (int rt = 0; rt < 4; rt++) {
        f32x4 acc0 = __builtin_amdgcn_mfma_f32_16x16x32_bf16(a[rt][0], b00, ci0, 0, 0, 0);
        acc0 = __builtin_amdgcn_mfma_f32_16x16x32_bf16(a[rt][1], b01, acc0, 0, 0, 0);
        f32x4 acc1 = __builtin_amdgcn_mfma_f32_16x16x32_bf16(a[rt][0], b10, ci1, 0, 0, 0);
        acc1 = __builtin_amdgcn_mfma_f32_16x16x32_bf16(a[rt][1], b11, acc1, 0, 0, 0);
#pragma unroll
        for (int j = 0; j < 4; j++) {
          if (acc0[j] > bestT[rt][j]) { bestT[rt][j] = acc0[j]; bestM[rt][j] = mi; }
          if (acc1[j] > bestT[rt][j]) { bestT[rt][j] = acc1[j]; bestM[rt][j] = mi + 16; }
        }
      }
    }
    nv0 = nv0n; nv1 = nv1n;
    mi += 32;
    __syncthreads();  // buf1 staged; buf0 free

    // ===== step s+1: read buf1, stage s+2 -> buf0 =====
    gld_lds16(cbb + (sbyte & CBBYTEMASK), ldst0);
    sbyte += 4096;
    nxt = (uint32_t)(nb + (s + 2) * 32);
    nv0n = nc2h[nxt & NCMASK];
    nv1n = nc2h[(nxt + 16) & NCMASK];
    {
      const char* sb = stage[1];
      bf16x8 b00 = *(const bf16x8*)(sb + o00);
      bf16x8 b01 = *(const bf16x8*)(sb + o01);
      bf16x8 b10 = *(const bf16x8*)(sb + o10);
      bf16x8 b11 = *(const bf16x8*)(sb + o11);
      f32x4 ci0 = {nv0, nv0, nv0, nv0};
      f32x4 ci1 = {nv1, nv1, nv1, nv1};
#pragma unroll
      for (int rt = 0; rt < 4; rt++) {
        f32x4 acc0 = __builtin_amdgcn_mfma_f32_16x16x32_bf16(a[rt][0], b00, ci0, 0, 0, 0);
        acc0 = __builtin_amdgcn_mfma_f32_16x16x32_bf16(a[rt][1], b01, acc0, 0, 0, 0);
        f32x4 acc1 = __builtin_amdgcn_mfma_f32_16x16x32_bf16(a[rt][0], b10, ci1, 0, 0, 0);
        acc1 = __builtin_amdgcn_mfma_f32_16x16x32_bf16(a[rt][1], b11, acc1, 0, 0, 0);
#pragma unroll
        for (int j = 0; j < 4; j++) {
          if (acc0[j] > bestT[rt][j]) { bestT[rt][j] = acc0[j]; bestM[rt][j] = mi; }
          if (acc1[j] > bestT[rt][j]) { bestT[rt][j] = acc1[j]; bestM[rt][j] = mi + 16; }
        }
      }
    }
    nv0 = nv0n; nv1 = nv1n;
    mi += 32;
    __syncthreads();  // buf0 staged; buf1 free
  }

  // ---- butterfly argmax across the 16 lanes sharing each row; write partials ----
#pragma unroll
  for (int rt = 0; rt < 4; rt++) {
#pragma unroll
    for (int j = 0; j < 4; j++) {
      float bt = bestT[rt][j];
      int bm = bestM[rt][j];
#pragma unroll
      for (int off = 1; off < 16; off <<= 1) {
        float ot = __shfl_xor(bt, off);
        int om = __shfl_xor(bm, off);
        if (ot > bt || (ot == bt && om < bm)) {
          bt = ot;
          bm = om;
        }
      }
      if (col == 0) {
        const int row = rowbase + rt * 16 + quad * 4 + j;
        tarr[row * NSPLIT + stripe] = bt;
        marr[row * NSPLIT + stripe] = bm;
      }
    }
  }
}

__global__ __launch_bounds__(256) void nn_final(const float* __restrict__ tarr,
                                                const int* __restrict__ marr,
                                                const float* __restrict__ x2arr,
                                                int* __restrict__ out) {
  const int row = blockIdx.x * blockDim.x + threadIdx.x;
  if (row >= NROWS) return;
  float bt = tarr[row * NSPLIT];
  int bm = marr[row * NSPLIT];
#pragma unroll
  for (int s = 1; s < NSPLIT; s++) {
    float t = tarr[row * NSPLIT + s];
    int m = marr[row * NSPLIT + s];
    if (t > bt || (t == bt && m < bm)) {
      bt = t;
      bm = m;
    }
  }
  const float d2 = fmaf(-2.0f, bt, x2arr[row]);  // min squared distance
  out[row] = (d2 <= 0.1f) ? bm : -1;
}

extern "C" void kernel_launch(void* const* d_in, const int* in_sizes, int n_in,
                              void* d_out, int out_size, void* d_ws, size_t ws_size,
                              hipStream_t stream) {
  const float* x = (const float*)d_in[0];      // [65536][64] fp32
  const float* codes = (const float*)d_in[1];  // [4096][64] fp32
  int* out = (int*)d_out;                      // [65536] int32

  char* ws = (char*)d_ws;
  __bf16* cb = (__bf16*)ws;                     // 512 KB
  float* nc2h = (float*)(ws + 0x080000);        // 16 KB
  float* tarr = (float*)(ws + 0x100000);        // 1 MB
  int* marr = (int*)(ws + 0x200000);            // 1 MB
  float* x2arr = (float*)(ws + 0x300000);       // 256 KB

  prep_codes_k<<<256, 256, 0, stream>>>(codes, nc2h, cb);
  nn_main<<<1024, 256, 0, stream>>>(x, cb, nc2h, tarr, marr, x2arr);
  nn_final<<<256, 256, 0, stream>>>(tarr, marr, x2arr, out);
}